// Round 12
// baseline (473.710 us; speedup 1.0000x reference)
//
#include <hip/hip_runtime.h>
#include <hip/hip_bf16.h>
#include <cstdint>
#include <cstddef>

// Problem constants (from reference)
#define B_    32
#define N_    1024
#define DEG_  8
#define FIN_  512
#define H_    1024
#define OUT_  10
#define E_    (B_ * N_ * DEG_)   // 262144
#define NN1_  (B_ * N_)          // 32768
#define K1_   (N_ / 2)           // 512
#define NN2_  (B_ * K1_)         // 16384
#define K2_   (N_ / 4)           // 256
#define EPS_  1e-5f
#define ECAP_ (N_ * DEG_)        // 8192 edges per graph (fixed capacity)
#define CAP2_ 64                 // stage-2 per-node CSR capacity (max indeg ~30)

// ---------------- workspace layout (bytes) ----------------
constexpr size_t OFF_CONV1 = 0;                                   // NN1 x H bf16 (64 MiB)
constexpr size_t OFF_XAGG  = OFF_CONV1 + (size_t)NN1_ * H_ * 2;   // NN1 x FIN bf16; stage2: hagg2
constexpr size_t OFF_HPOOL = OFF_XAGG + (size_t)NN1_ * FIN_ * 2;  // NN2 x H bf16
constexpr size_t OFF_CONV2 = OFF_HPOOL + (size_t)NN2_ * H_ * 2;   // NN2 x H bf16
constexpr size_t OFF_CNT1  = OFF_CONV2 + (size_t)NN2_ * H_ * 2;   // NN1 ints (zeroed)
constexpr size_t OFF_CNT2  = OFF_CNT1 + (size_t)NN1_ * 4;         // NN2 ints (written directly)
constexpr size_t OFF_BN1   = OFF_CNT2 + (size_t)NN2_ * 4;         // 2H floats raw sums (zeroed)
constexpr size_t OFF_BN2   = OFF_BN1 + (size_t)2 * H_ * 4;
constexpr size_t OFF_X1    = OFF_BN2 + (size_t)2 * H_ * 4;        // B*H floats (zeroed)
constexpr size_t OFF_X2    = OFF_X1 + (size_t)B_ * H_ * 4;
constexpr size_t OFF_ZWS   = OFF_X2 + (size_t)B_ * H_ * 4;        // B*512 floats (zeroed)
constexpr size_t ZERO_BASE = OFF_CNT1;
constexpr size_t ZERO_BYTES = OFF_ZWS + (size_t)B_ * 512 * 4 - ZERO_BASE;
constexpr size_t OFF_PTR1  = OFF_ZWS + (size_t)B_ * 512 * 4;
constexpr size_t OFF_PTR2  = OFF_PTR1 + (size_t)(NN1_ + 64) * 4;
constexpr size_t OFF_CSR1  = OFF_PTR2 + (size_t)(NN2_ + 64) * 4;
constexpr size_t OFF_CSR2  = OFF_CSR1 + (size_t)E_ * 4;           // NN2*CAP2 ints (4 MiB)
constexpr size_t OFF_SC1   = OFF_CSR2 + (size_t)NN2_ * CAP2_ * 4;
constexpr size_t OFF_SC2   = OFF_SC1 + (size_t)NN1_ * 4;
constexpr size_t OFF_PERM1 = OFF_SC2 + (size_t)NN2_ * 4;
constexpr size_t OFF_VAL1  = OFF_PERM1 + (size_t)NN2_ * 4;
constexpr size_t OFF_PERM2 = OFF_VAL1 + (size_t)NN2_ * 4;
constexpr size_t OFF_VAL2  = OFF_PERM2 + (size_t)(B_ * K2_) * 4;
constexpr size_t OFF_NEWID = OFF_VAL2 + (size_t)(B_ * K2_) * 4;   // NN1 ints (0xFF)
constexpr size_t OFF_PNORM = OFF_NEWID + (size_t)NN1_ * 4;        // padded
constexpr size_t OFF_WT1   = OFF_PNORM + 256;                     // H*FIN bf16
constexpr size_t OFF_WT2   = OFF_WT1 + (size_t)H_ * FIN_ * 2;     // H*H bf16
constexpr size_t OFF_XBF   = OFF_WT2 + (size_t)H_ * H_ * 2;       // NN1 x FIN bf16
// total ≈ 234 MiB

// ---------------- helpers ----------------
typedef short short8 __attribute__((ext_vector_type(8)));
typedef float f32x4 __attribute__((ext_vector_type(4)));

__device__ inline unsigned short f2bf(float f) {
  uint32_t u = __float_as_uint(f);
  u += 0x7fffu + ((u >> 16) & 1u);   // RNE
  return (unsigned short)(u >> 16);
}
__device__ inline float bf2f(unsigned short u) {
  return __uint_as_float(((uint32_t)u) << 16);
}

__device__ inline void load_lds16(const void* g, void* l) {
  __builtin_amdgcn_global_load_lds(
      (const __attribute__((address_space(1))) uint32_t*)g,
      (__attribute__((address_space(3))) uint32_t*)l, 16, 0, 0);
}

// bn affine from raw sums: a = g*rsqrt(var+eps), c = be - mean*a
__device__ inline void bn_affine(float sum, float sumsq, float g, float be,
                                 float inv_n, float& a, float& c) {
  float mean = sum * inv_n;
  float var = sumsq * inv_n - mean * mean;
  a = g * rsqrtf(var + EPS_);
  c = be - mean * a;
}

// ---------------- kernels ----------------

// Fused prep: tobf [0,16384) | count [16384,17408) | wt1 [17408,17920)
//             wt2 [17920,18944) | pnorm [18944,18946)
#define PREP_BLOCKS 18946
__global__ __launch_bounds__(256) void k_prep(const float* __restrict__ x,
                                              const int* __restrict__ dstv,
                                              const float* __restrict__ W1,
                                              const float* __restrict__ W2,
                                              const float* __restrict__ p1,
                                              const float* __restrict__ p2,
                                              unsigned short* __restrict__ xbf,
                                              int* __restrict__ cnt,
                                              unsigned short* __restrict__ Wt1,
                                              unsigned short* __restrict__ Wt2,
                                              float* __restrict__ pn) {
  __shared__ float sh[32][33];
  __shared__ float red[256];
  int bid = blockIdx.x, t = threadIdx.x;
  if (bid < 16384) {                      // fp32 -> bf16 convert of x
    size_t i = ((size_t)bid * 256 + t) * 4;
    float4 v = *(const float4*)&x[i];
    ushort4 o = {f2bf(v.x), f2bf(v.y), f2bf(v.z), f2bf(v.w)};
    *(ushort4*)&xbf[i] = o;
  } else if (bid < 17408) {               // edge dst count
    int e = (bid - 16384) * 256 + t;
    atomicAdd(&cnt[dstv[e]], 1);
  } else if (bid < 18944) {               // weight transpose -> bf16
    const float* W; unsigned short* Wt; int K, N, r;
    if (bid < 17920) { W = W1; Wt = Wt1; K = FIN_; N = H_; r = bid - 17408; }
    else             { W = W2; Wt = Wt2; K = H_;   N = H_; r = bid - 17920; }
    int bx = r & 31, by = r >> 5;
    int k0 = by * 32, n0 = bx * 32;
    int tx = t & 31, ty = t >> 5;
    for (int i = ty; i < 32; i += 8)
      sh[i][tx] = W[(size_t)(k0 + i) * N + n0 + tx];
    __syncthreads();
    for (int i = ty; i < 32; i += 8)
      Wt[(size_t)(n0 + i) * K + k0 + tx] = f2bf(sh[tx][i]);
  } else {                                // pnorm
    const float* p = (bid == 18944) ? p1 : p2;
    float s = 0.f;
    for (int i = t; i < H_; i += 256) s += p[i] * p[i];
    red[t] = s; __syncthreads();
    for (int st = 128; st > 0; st >>= 1) { if (t < st) red[t] += red[t + st]; __syncthreads(); }
    if (t == 0) pn[bid - 18944] = sqrtf(red[0]);
  }
}

// Fused per-graph scan + CSR fill (stage 1). One block per graph; edges of
// graph g occupy [g*ECAP_, (g+1)*ECAP_) in edge_index, dst in [g*N,(g+1)*N).
__global__ __launch_bounds__(256) void k_scanfill1(const int* __restrict__ cnt,
                                                   const int* __restrict__ srcv,
                                                   const int* __restrict__ dstv,
                                                   int* __restrict__ ptr,
                                                   int* __restrict__ csr) {
  __shared__ int ptr_l[1024];
  __shared__ int fl[1024];
  __shared__ int tot[256];
  int g = blockIdx.x, t = threadIdx.x;
  int base = g * N_ + t * 4;
  int c0 = cnt[base], c1 = cnt[base + 1], c2 = cnt[base + 2], c3 = cnt[base + 3];
  int s = c0 + c1 + c2 + c3;
  tot[t] = s;
  __syncthreads();
  for (int off = 1; off < 256; off <<= 1) {
    int v = (t >= off) ? tot[t - off] : 0;
    __syncthreads();
    tot[t] += v;
    __syncthreads();
  }
  int pre = (t == 0) ? 0 : tot[t - 1];
  int gb = g * ECAP_;
  int l0 = pre, l1 = l0 + c0, l2 = l1 + c1, l3 = l2 + c2;
  ptr_l[t * 4 + 0] = l0; ptr_l[t * 4 + 1] = l1;
  ptr_l[t * 4 + 2] = l2; ptr_l[t * 4 + 3] = l3;
  fl[t * 4 + 0] = 0; fl[t * 4 + 1] = 0; fl[t * 4 + 2] = 0; fl[t * 4 + 3] = 0;
  ptr[base + 0] = gb + l0; ptr[base + 1] = gb + l1;
  ptr[base + 2] = gb + l2; ptr[base + 3] = gb + l3;
  __syncthreads();
  for (int e = gb + t; e < gb + ECAP_; e += 256) {
    int dl = dstv[e] - g * N_;
    int pos = ptr_l[dl] + atomicAdd(&fl[dl], 1);
    csr[gb + pos] = srcv[e];
  }
}

// Build stage-2 CSR from stage-1 CSR (no edge_index pass): one wave per kept
// node i; filter csr1[perm1[i]]'s source list through newid, ballot-compact
// into csr2[i*CAP2_ ..]; cnt2/ptr2 written directly.
__global__ __launch_bounds__(256) void k_build2(const int* __restrict__ perm1,
                                                const int* __restrict__ newid,
                                                const int* __restrict__ ptr1,
                                                const int* __restrict__ cnt1,
                                                const int* __restrict__ csr1,
                                                int* __restrict__ csr2,
                                                int* __restrict__ ptr2,
                                                int* __restrict__ cnt2) {
  int i = blockIdx.x * 4 + (threadIdx.x >> 6);
  int lane = threadIdx.x & 63;
  int old = perm1[i];
  int e0 = ptr1[old], n = cnt1[old];
  int base = i * CAP2_;
  int total = 0;
  for (int b = 0; b < n; b += 64) {
    int l = b + lane;
    int ns = -1;
    if (l < n) ns = newid[csr1[e0 + l]];
    bool valid = (l < n) && (ns >= 0);
    unsigned long long mask = __ballot(valid);
    int pos = __popcll(mask & ((1ull << lane) - 1ull));
    if (valid && total + pos < CAP2_) csr2[base + total + pos] = ns;
    total += __popcll(mask);
  }
  if (lane == 0) { cnt2[i] = total; ptr2[i] = base; }
}

// Aggregation (bf16 in -> bf16 out), XCD-swizzled slabs. e1 = e0 + cnt[v].
__global__ void k_agg_bf(const unsigned short* __restrict__ X,
                         const int* __restrict__ csr,
                         const int* __restrict__ ptr,
                         const int* __restrict__ cnt,
                         unsigned short* __restrict__ out, int F) {
  int bid = blockIdx.x;
  int slab = gridDim.x >> 3;
  int v = (bid & 7) * slab + (bid >> 3);
  int c = threadIdx.x * 4;
  float degv = 1.0f + (float)cnt[v];
  float dinvv = rsqrtf(degv);
  float inv = 1.0f / degv;
  ushort4 xu = *(const ushort4*)&X[(size_t)v * F + c];
  float4 acc = {bf2f(xu.x) * inv, bf2f(xu.y) * inv, bf2f(xu.z) * inv, bf2f(xu.w) * inv};
  int e0 = ptr[v], e1 = e0 + cnt[v];
  for (int e = e0; e < e1; ++e) {
    int s = csr[e];
    float w = dinvv * rsqrtf(1.0f + (float)cnt[s]);
    ushort4 xs = *(const ushort4*)&X[(size_t)s * F + c];
    acc.x += bf2f(xs.x) * w; acc.y += bf2f(xs.y) * w;
    acc.z += bf2f(xs.z) * w; acc.w += bf2f(xs.w) * w;
  }
  ushort4 o = {f2bf(acc.x), f2bf(acc.y), f2bf(acc.z), f2bf(acc.w)};
  *(ushort4*)&out[(size_t)v * F + c] = o;
}

// bf16 MFMA GEMM: 256(m) x 128(n) tile, BK=64 (XOR-swizzled segments),
// 512 threads = 8 waves (4x2). bf16 C via LDS-staged coalesced stores;
// fused per-column sum/sumsq; XCD-banded m-tiles.
__global__ __launch_bounds__(512) void k_gemm_bf(const unsigned short* __restrict__ A,
                                                 const unsigned short* __restrict__ Bt,
                                                 const float* __restrict__ bias,
                                                 unsigned short* __restrict__ C,
                                                 float* __restrict__ bn,
                                                 int M, int N, int K) {
  __shared__ __align__(16) char smem[49152];            // 48 KiB
  unsigned short* sA  = (unsigned short*)smem;          // 256x64 = 32 KiB
  unsigned short* sB  = (unsigned short*)(smem + 256 * 64 * 2);  // 128x64 = 16 KiB
  unsigned short* epi = (unsigned short*)smem;          // 128x136 (epilogue, 34 KiB)

  const int tid = threadIdx.x;
  const int lane = tid & 63;
  const int w = tid >> 6;
  const int wy = w >> 1, wx = w & 1;
  int lin = blockIdx.y * gridDim.x + blockIdx.x;
  int nt = gridDim.x;
  int mchunk = gridDim.y >> 3;
  int xcd = lin & 7;
  int idx = lin >> 3;
  int mtile = xcd * mchunk + idx / nt;
  int ntile = idx % nt;
  const int gm = mtile * 256, gn = ntile * 128;

  const int m_l = lane & 15, kq = lane >> 4;
  const int srow = lane >> 3;           // 0..7: row within 8-row chunk
  const int ssegi = lane & 7;           // 0..7: LDS segment slot

  f32x4 acc[4][4] = {};

  for (int k0 = 0; k0 < K; k0 += 64) {
    __syncthreads();
#pragma unroll
    for (int i = 0; i < 4; ++i) {
      int row = w * 32 + i * 8 + srow;
      int gseg = ssegi ^ (row & 7);
      load_lds16(&A[(size_t)(gm + row) * K + k0 + gseg * 8],
                 (void*)&sA[(size_t)(w * 32 + i * 8) * 64 + (size_t)lane * 8]);
    }
#pragma unroll
    for (int i = 0; i < 2; ++i) {
      int row = w * 16 + i * 8 + srow;
      int gseg = ssegi ^ (row & 7);
      load_lds16(&Bt[(size_t)(gn + row) * K + k0 + gseg * 8],
                 (void*)&sB[(size_t)(w * 16 + i * 8) * 64 + (size_t)lane * 8]);
    }
    __syncthreads();

#pragma unroll
    for (int h = 0; h < 2; ++h) {
      short8 af[4], bfr[4];
      int gseg = h * 4 + kq;
#pragma unroll
      for (int mi = 0; mi < 4; ++mi) {
        int row = wy * 64 + mi * 16 + m_l;
        int s = gseg ^ (row & 7);
        af[mi] = *(const short8*)&sA[(size_t)row * 64 + s * 8];
      }
#pragma unroll
      for (int ni = 0; ni < 4; ++ni) {
        int row = wx * 64 + ni * 16 + m_l;
        int s = gseg ^ (row & 7);
        bfr[ni] = *(const short8*)&sB[(size_t)row * 64 + s * 8];
      }
#pragma unroll
      for (int mi = 0; mi < 4; ++mi)
#pragma unroll
        for (int ni = 0; ni < 4; ++ni)
          acc[mi][ni] = __builtin_amdgcn_mfma_f32_16x16x32_bf16(af[mi], bfr[ni], acc[mi][ni], 0, 0, 0);
    }
  }

  const int r0 = kq * 4;   // C/D: col = lane&15, row = (lane>>4)*4 + reg
  float bvv[4];
#pragma unroll
  for (int ni = 0; ni < 4; ++ni) {
    int col = gn + wx * 64 + ni * 16 + m_l;
    bvv[ni] = bias[col];
    float s = 0.f, s2 = 0.f;
#pragma unroll
    for (int mi = 0; mi < 4; ++mi)
#pragma unroll
      for (int r = 0; r < 4; ++r) {
        float v = acc[mi][ni][r] + bvv[ni];
        s += v; s2 += v * v;
      }
    s += __shfl_xor(s, 16, 64);  s2 += __shfl_xor(s2, 16, 64);
    s += __shfl_xor(s, 32, 64);  s2 += __shfl_xor(s2, 32, 64);
    if (kq == 0) {
      atomicAdd(&bn[col], s);
      atomicAdd(&bn[N + col], s2);
    }
  }

  // two-phase LDS-staged coalesced C write
#pragma unroll
  for (int p = 0; p < 2; ++p) {
    __syncthreads();
    if ((wy >> 1) == p) {
      int lr = (wy & 1) * 64;
#pragma unroll
      for (int ni = 0; ni < 4; ++ni) {
        int lcol = wx * 64 + ni * 16 + m_l;
#pragma unroll
        for (int mi = 0; mi < 4; ++mi)
#pragma unroll
          for (int r = 0; r < 4; ++r)
            epi[(size_t)(lr + mi * 16 + r0 + r) * 136 + lcol] = f2bf(acc[mi][ni][r] + bvv[ni]);
      }
    }
    __syncthreads();
#pragma unroll
    for (int i = 0; i < 4; ++i) {
      int cch = tid + i * 512;
      int row = cch >> 4, seg = cch & 15;
      uint4 v = *(const uint4*)&epi[(size_t)row * 136 + seg * 8];
      *(uint4*)&C[(size_t)(gm + p * 128 + row) * N + gn + seg * 8] = v;
    }
  }
}

// score[v] = tanh(dot(relu(x*a+c), p)/||p||); bn affine computed from raw sums
__global__ __launch_bounds__(256) void k_score(const unsigned short* __restrict__ X,
                                               const float* __restrict__ bnsum,
                                               const float* __restrict__ gam,
                                               const float* __restrict__ bet,
                                               float inv_n,
                                               const float* __restrict__ p,
                                               const float* __restrict__ pnorm,
                                               float* __restrict__ score) {
  __shared__ float wred[4];
  int v = blockIdx.x;
  int t = threadIdx.x;
  int c = t * 4;
  float4 sm = *(const float4*)&bnsum[c];
  float4 sq = *(const float4*)&bnsum[H_ + c];
  float4 gg = *(const float4*)&gam[c];
  float4 bb = *(const float4*)&bet[c];
  float a0, c0, a1, c1, a2, c2, a3, c3;
  bn_affine(sm.x, sq.x, gg.x, bb.x, inv_n, a0, c0);
  bn_affine(sm.y, sq.y, gg.y, bb.y, inv_n, a1, c1);
  bn_affine(sm.z, sq.z, gg.z, bb.z, inv_n, a2, c2);
  bn_affine(sm.w, sq.w, gg.w, bb.w, inv_n, a3, c3);
  ushort4 xu = *(const ushort4*)&X[(size_t)v * H_ + c];
  float hx = fmaxf(bf2f(xu.x) * a0 + c0, 0.f);
  float hy = fmaxf(bf2f(xu.y) * a1 + c1, 0.f);
  float hz = fmaxf(bf2f(xu.z) * a2 + c2, 0.f);
  float hw = fmaxf(bf2f(xu.w) * a3 + c3, 0.f);
  float4 p4 = *(const float4*)&p[c];
  float s = hx * p4.x + hy * p4.y + hz * p4.z + hw * p4.w;
#pragma unroll
  for (int off = 1; off < 64; off <<= 1) s += __shfl_xor(s, off, 64);
  if ((t & 63) == 0) wred[t >> 6] = s;
  __syncthreads();
  if (t == 0) score[v] = tanhf((wred[0] + wred[1] + wred[2] + wred[3]) / pnorm[0]);
}

// per-graph exact descending bitonic sort (tie: smaller index first), 256 threads
__global__ __launch_bounds__(256) void k_topk(const float* __restrict__ score,
                                              int nper, int k,
                                              int* __restrict__ perm,
                                              float* __restrict__ val,
                                              int* __restrict__ newid) {
  __shared__ float sk[1024];
  __shared__ int si[1024];
  int g = blockIdx.x, t = threadIdx.x;
  for (int i = t; i < nper; i += 256) { sk[i] = score[g * nper + i]; si[i] = i; }
  __syncthreads();
  int pairs = nper >> 1;
  for (int k2 = 2; k2 <= nper; k2 <<= 1) {
    for (int j = k2 >> 1; j > 0; j >>= 1) {
      for (int p = t; p < pairs; p += 256) {
        int i = ((p & ~(j - 1)) << 1) | (p & (j - 1));
        int ix = i | j;
        float a = sk[i], b = sk[ix];
        int ia = si[i], ib = si[ix];
        bool aFirst = (a > b) || (a == b && ia < ib);
        bool dirDesc = ((i & k2) == 0);
        if (dirDesc ? (!aFirst) : aFirst) {
          sk[i] = b; sk[ix] = a; si[i] = ib; si[ix] = ia;
        }
      }
      __syncthreads();
    }
  }
  for (int i = t; i < k; i += 256) {
    perm[g * k + i] = g * nper + si[i];
    val[g * k + i] = sk[i];
    if (newid) newid[g * nper + si[i]] = g * k + i;
  }
}

// hpool[i] = relu(conv[perm[i]]*a+c) * val[i]   (bf16 -> bf16, BN fused from raw sums)
__global__ __launch_bounds__(256) void k_pool_bn(const unsigned short* __restrict__ Hm,
                                                 const float* __restrict__ bnsum,
                                                 const float* __restrict__ gam,
                                                 const float* __restrict__ bet,
                                                 float inv_n,
                                                 const int* __restrict__ perm,
                                                 const float* __restrict__ val,
                                                 unsigned short* __restrict__ out) {
  int i = blockIdx.x;
  int c = threadIdx.x * 4;
  int old = perm[i];
  float vv = val[i];
  float4 sm = *(const float4*)&bnsum[c];
  float4 sq = *(const float4*)&bnsum[H_ + c];
  float4 gg = *(const float4*)&gam[c];
  float4 bb = *(const float4*)&bet[c];
  float a0, c0, a1, c1, a2, c2, a3, c3;
  bn_affine(sm.x, sq.x, gg.x, bb.x, inv_n, a0, c0);
  bn_affine(sm.y, sq.y, gg.y, bb.y, inv_n, a1, c1);
  bn_affine(sm.z, sq.z, gg.z, bb.z, inv_n, a2, c2);
  bn_affine(sm.w, sq.w, gg.w, bb.w, inv_n, a3, c3);
  ushort4 xu = *(const ushort4*)&Hm[(size_t)old * H_ + c];
  ushort4 o = {f2bf(fmaxf(bf2f(xu.x) * a0 + c0, 0.f) * vv),
               f2bf(fmaxf(bf2f(xu.y) * a1 + c1, 0.f) * vv),
               f2bf(fmaxf(bf2f(xu.z) * a2 + c2, 0.f) * vv),
               f2bf(fmaxf(bf2f(xu.w) * a3 + c3, 0.f) * vv)};
  *(ushort4*)&out[(size_t)i * H_ + c] = o;
}

// partial column-mean (bf16 in), z-split; out pre-zeroed fp32
__global__ __launch_bounds__(256) void k_mean(const unsigned short* __restrict__ X,
                                              float* __restrict__ out,
                                              int k, int rows_per_blk) {
  int g = blockIdx.x;
  int col = blockIdx.y * 256 + threadIdx.x;
  int j0 = blockIdx.z * rows_per_blk;
  float s = 0.f;
  for (int j = j0; j < j0 + rows_per_blk; ++j)
    s += bf2f(X[(size_t)(g * k + j) * H_ + col]);
  atomicAdd(&out[g * H_ + col], s / (float)k);
}

// partial scaled column-mean with fused BN+ReLU, z-split; out pre-zeroed
__global__ __launch_bounds__(256) void k_mean_scaled_bn(const unsigned short* __restrict__ X,
                                                        const float* __restrict__ bnsum,
                                                        const float* __restrict__ gam,
                                                        const float* __restrict__ bet,
                                                        float inv_n,
                                                        const int* __restrict__ perm,
                                                        const float* __restrict__ val,
                                                        float* __restrict__ out,
                                                        int k, int rows_per_blk) {
  int g = blockIdx.x;
  int col = blockIdx.y * 256 + threadIdx.x;
  int j0 = blockIdx.z * rows_per_blk;
  float a, cc;
  bn_affine(bnsum[col], bnsum[H_ + col], gam[col], bet[col], inv_n, a, cc);
  float s = 0.f;
  for (int j = j0; j < j0 + rows_per_blk; ++j) {
    int r = perm[g * k + j];
    float h = fmaxf(bf2f(X[(size_t)r * H_ + col]) * a + cc, 0.f);
    s += val[g * k + j] * h;
  }
  atomicAdd(&out[g * H_ + col], s / (float)k);
}

// head part 1: grid (8 z-chunks, 4 graph-quads); Wf chunk reused across 8 graphs
__global__ __launch_bounds__(512) void k_head1(const float* __restrict__ x1,
                                               const float* __restrict__ x2,
                                               const float* __restrict__ Wf,
                                               float* __restrict__ zws) {
  __shared__ float sx[8][128];
  int z = blockIdx.x, gq = blockIdx.y, t = threadIdx.x;
  int k0 = z * 128;
  for (int i = t; i < 8 * 128; i += 512) {
    int gl = i >> 7, k = i & 127;
    int g = gq * 8 + gl;
    sx[gl][k] = x1[g * H_ + k0 + k] + x2[g * H_ + k0 + k];
  }
  __syncthreads();
  float acc[8] = {};
  for (int k = 0; k < 128; ++k) {
    float w = Wf[(size_t)(k0 + k) * 512 + t];
#pragma unroll
    for (int gl = 0; gl < 8; ++gl) acc[gl] += sx[gl][k] * w;
  }
#pragma unroll
  for (int gl = 0; gl < 8; ++gl)
    atomicAdd(&zws[(gq * 8 + gl) * 512 + t], acc[gl]);
}

// head part 2: z = relu(zws+bf); out = z@Wf1 + bf1
__global__ __launch_bounds__(512) void k_head2(const float* __restrict__ zws,
                                               const float* __restrict__ bf,
                                               const float* __restrict__ Wf1,
                                               const float* __restrict__ bf1,
                                               float* __restrict__ out) {
  __shared__ float red[512];
  int g = blockIdx.x, t = threadIdx.x;
  float zv = fmaxf(zws[g * 512 + t] + bf[t], 0.f);
  for (int o = 0; o < OUT_; ++o) {
    red[t] = zv * Wf1[t * OUT_ + o];
    __syncthreads();
    for (int s = 256; s > 0; s >>= 1) { if (t < s) red[t] += red[t + s]; __syncthreads(); }
    if (t == 0) out[g * OUT_ + o] = red[0] + bf1[o];
    __syncthreads();
  }
}

// ---------------- launch ----------------
extern "C" void kernel_launch(void* const* d_in, const int* in_sizes, int n_in,
                              void* d_out, int out_size, void* d_ws, size_t ws_size,
                              hipStream_t stream) {
  (void)in_sizes; (void)n_in; (void)out_size; (void)ws_size;
  const float* x   = (const float*)d_in[0];
  const int*   ei  = (const int*)d_in[1];
  const float* W1  = (const float*)d_in[3];
  const float* b1  = (const float*)d_in[4];
  const float* g1  = (const float*)d_in[5];
  const float* be1 = (const float*)d_in[6];
  const float* p1  = (const float*)d_in[7];
  const float* W2  = (const float*)d_in[8];
  const float* b2  = (const float*)d_in[9];
  const float* g2  = (const float*)d_in[10];
  const float* be2 = (const float*)d_in[11];
  const float* p2  = (const float*)d_in[12];
  const float* Wf  = (const float*)d_in[13];
  const float* bf  = (const float*)d_in[14];
  const float* Wf1 = (const float*)d_in[15];
  const float* bf1 = (const float*)d_in[16];
  const int* srcv = ei;
  const int* dstv = ei + E_;

  char* ws = (char*)d_ws;
  unsigned short* conv1 = (unsigned short*)(ws + OFF_CONV1);
  unsigned short* xagg  = (unsigned short*)(ws + OFF_XAGG);
  unsigned short* hagg2 = (unsigned short*)(ws + OFF_XAGG);  // aliases xagg (dead by then)
  unsigned short* hpool = (unsigned short*)(ws + OFF_HPOOL);
  unsigned short* conv2 = (unsigned short*)(ws + OFF_CONV2);
  unsigned short* xbf   = (unsigned short*)(ws + OFF_XBF);
  int* cnt1    = (int*)(ws + OFF_CNT1);
  int* cnt2    = (int*)(ws + OFF_CNT2);
  float* bn1   = (float*)(ws + OFF_BN1);
  float* bn2   = (float*)(ws + OFF_BN2);
  int* ptr1    = (int*)(ws + OFF_PTR1);
  int* ptr2    = (int*)(ws + OFF_PTR2);
  int* csr1    = (int*)(ws + OFF_CSR1);
  int* csr2    = (int*)(ws + OFF_CSR2);
  float* sc1   = (float*)(ws + OFF_SC1);
  float* sc2   = (float*)(ws + OFF_SC2);
  int* perm1   = (int*)(ws + OFF_PERM1);
  float* val1  = (float*)(ws + OFF_VAL1);
  int* perm2   = (int*)(ws + OFF_PERM2);
  float* val2  = (float*)(ws + OFF_VAL2);
  int* newid1  = (int*)(ws + OFF_NEWID);
  float* pnorm = (float*)(ws + OFF_PNORM);
  float* x1    = (float*)(ws + OFF_X1);
  float* x2    = (float*)(ws + OFF_X2);
  float* zws   = (float*)(ws + OFF_ZWS);
  unsigned short* Wt1 = (unsigned short*)(ws + OFF_WT1);
  unsigned short* Wt2 = (unsigned short*)(ws + OFF_WT2);

  hipMemsetAsync(ws + ZERO_BASE, 0, ZERO_BYTES, stream);
  hipMemsetAsync(ws + OFF_NEWID, 0xFF, (size_t)NN1_ * 4, stream);  // new_id = -1

  // fused prep: x->bf16, dst count, W1^T, W2^T, pnorms
  k_prep<<<PREP_BLOCKS, 256, 0, stream>>>(x, dstv, W1, W2, p1, p2,
                                          xbf, cnt1, Wt1, Wt2, pnorm);

  // ---- stage 1 ----
  k_scanfill1<<<B_, 256, 0, stream>>>(cnt1, srcv, dstv, ptr1, csr1);
  k_agg_bf<<<NN1_, FIN_ / 4, 0, stream>>>(xbf, csr1, ptr1, cnt1, xagg, FIN_);
  k_gemm_bf<<<dim3(H_ / 128, NN1_ / 256), 512, 0, stream>>>(xagg, Wt1, b1, conv1, bn1, NN1_, H_, FIN_);
  k_score<<<NN1_, 256, 0, stream>>>(conv1, bn1, g1, be1, 1.0f / (float)NN1_, p1, pnorm + 0, sc1);
  k_topk<<<B_, 256, 0, stream>>>(sc1, N_, K1_, perm1, val1, newid1);
  k_pool_bn<<<NN2_, 256, 0, stream>>>(conv1, bn1, g1, be1, 1.0f / (float)NN1_, perm1, val1, hpool);
  k_mean<<<dim3(B_, H_ / 256, 8), 256, 0, stream>>>(hpool, x1, K1_, K1_ / 8);

  // ---- stage 2 ----
  k_build2<<<NN2_ / 4, 256, 0, stream>>>(perm1, newid1, ptr1, cnt1, csr1, csr2, ptr2, cnt2);
  k_agg_bf<<<NN2_, H_ / 4, 0, stream>>>(hpool, csr2, ptr2, cnt2, hagg2, H_);
  k_gemm_bf<<<dim3(H_ / 128, NN2_ / 256), 512, 0, stream>>>(hagg2, Wt2, b2, conv2, bn2, NN2_, H_, H_);
  k_score<<<NN2_, 256, 0, stream>>>(conv2, bn2, g2, be2, 1.0f / (float)NN2_, p2, pnorm + 1, sc2);
  k_topk<<<B_, 256, 0, stream>>>(sc2, K1_, K2_, perm2, val2, nullptr);
  k_mean_scaled_bn<<<dim3(B_, H_ / 256, 4), 256, 0, stream>>>(conv2, bn2, g2, be2, 1.0f / (float)NN2_,
                                                              perm2, val2, x2, K2_, K2_ / 4);

  // ---- head ----
  k_head1<<<dim3(8, 4), 512, 0, stream>>>(x1, x2, Wf, zws);
  k_head2<<<B_, 512, 0, stream>>>(zws, bf, Wf1, bf1, (float*)d_out);
}

// Round 13
// 435.784 us; speedup vs baseline: 1.0870x; 1.0870x over previous
//
#include <hip/hip_runtime.h>
#include <hip/hip_bf16.h>
#include <cstdint>
#include <cstddef>

// Problem constants (from reference)
#define B_    32
#define N_    1024
#define DEG_  8
#define FIN_  512
#define H_    1024
#define OUT_  10
#define E_    (B_ * N_ * DEG_)   // 262144
#define NN1_  (B_ * N_)          // 32768
#define K1_   (N_ / 2)           // 512
#define NN2_  (B_ * K1_)         // 16384
#define K2_   (N_ / 4)           // 256
#define EPS_  1e-5f
#define ECAP_ (N_ * DEG_)        // 8192 edges per graph (fixed capacity)
#define CAP2_ 64                 // stage-2 per-node CSR capacity (max indeg ~35)

// ---------------- workspace layout (bytes) ----------------
constexpr size_t OFF_CONV1 = 0;                                   // NN1 x H bf16 (64 MiB)
constexpr size_t OFF_XAGG  = OFF_CONV1 + (size_t)NN1_ * H_ * 2;   // NN1 x FIN bf16; stage2: hagg2
constexpr size_t OFF_HPOOL = OFF_XAGG + (size_t)NN1_ * FIN_ * 2;  // NN2 x H bf16
constexpr size_t OFF_CONV2 = OFF_HPOOL + (size_t)NN2_ * H_ * 2;   // NN2 x H bf16
constexpr size_t OFF_CNT1  = OFF_CONV2 + (size_t)NN2_ * H_ * 2;   // NN1 ints (zeroed)
constexpr size_t OFF_FILL1 = OFF_CNT1 + (size_t)NN1_ * 4;         // NN1 ints (zeroed)
constexpr size_t OFF_BN1   = OFF_FILL1 + (size_t)NN1_ * 4;        // 2H floats raw sums (zeroed)
constexpr size_t OFF_BN2   = OFF_BN1 + (size_t)2 * H_ * 4;
constexpr size_t OFF_X1    = OFF_BN2 + (size_t)2 * H_ * 4;        // B*H floats (zeroed)
constexpr size_t OFF_X2    = OFF_X1 + (size_t)B_ * H_ * 4;
constexpr size_t OFF_ZWS   = OFF_X2 + (size_t)B_ * H_ * 4;        // B*512 floats (zeroed)
constexpr size_t ZERO_BASE = OFF_CNT1;
constexpr size_t ZERO_BYTES = OFF_ZWS + (size_t)B_ * 512 * 4 - ZERO_BASE;
constexpr size_t OFF_CNT2  = OFF_ZWS + (size_t)B_ * 512 * 4;      // NN2 ints (written directly)
constexpr size_t OFF_PTR1  = OFF_CNT2 + (size_t)NN2_ * 4;
constexpr size_t OFF_PTR2  = OFF_PTR1 + (size_t)(NN1_ + 64) * 4;
constexpr size_t OFF_CSR1  = OFF_PTR2 + (size_t)(NN2_ + 64) * 4;
constexpr size_t OFF_CSR2  = OFF_CSR1 + (size_t)E_ * 4;           // NN2*CAP2 ints (4 MiB)
constexpr size_t OFF_SC1   = OFF_CSR2 + (size_t)NN2_ * CAP2_ * 4;
constexpr size_t OFF_SC2   = OFF_SC1 + (size_t)NN1_ * 4;
constexpr size_t OFF_PERM1 = OFF_SC2 + (size_t)NN2_ * 4;
constexpr size_t OFF_VAL1  = OFF_PERM1 + (size_t)NN2_ * 4;
constexpr size_t OFF_PERM2 = OFF_VAL1 + (size_t)NN2_ * 4;
constexpr size_t OFF_VAL2  = OFF_PERM2 + (size_t)(B_ * K2_) * 4;
constexpr size_t OFF_NEWID = OFF_VAL2 + (size_t)(B_ * K2_) * 4;   // NN1 ints (0xFF)
constexpr size_t OFF_PNORM = OFF_NEWID + (size_t)NN1_ * 4;        // padded
constexpr size_t OFF_WT1   = OFF_PNORM + 256;                     // H*FIN bf16
constexpr size_t OFF_WT2   = OFF_WT1 + (size_t)H_ * FIN_ * 2;     // H*H bf16
constexpr size_t OFF_XBF   = OFF_WT2 + (size_t)H_ * H_ * 2;       // NN1 x FIN bf16
// total ≈ 234 MiB

// ---------------- helpers ----------------
typedef short short8 __attribute__((ext_vector_type(8)));
typedef float f32x4 __attribute__((ext_vector_type(4)));

__device__ inline unsigned short f2bf(float f) {
  uint32_t u = __float_as_uint(f);
  u += 0x7fffu + ((u >> 16) & 1u);   // RNE
  return (unsigned short)(u >> 16);
}
__device__ inline float bf2f(unsigned short u) {
  return __uint_as_float(((uint32_t)u) << 16);
}
__device__ inline float bflo(uint32_t w) { return __uint_as_float(w << 16); }
__device__ inline float bfhi(uint32_t w) { return __uint_as_float(w & 0xffff0000u); }
__device__ inline uint32_t pack2(float a, float b) {
  return (uint32_t)f2bf(a) | ((uint32_t)f2bf(b) << 16);
}

__device__ inline void load_lds16(const void* g, void* l) {
  __builtin_amdgcn_global_load_lds(
      (const __attribute__((address_space(1))) uint32_t*)g,
      (__attribute__((address_space(3))) uint32_t*)l, 16, 0, 0);
}

// bn affine from raw sums: a = g*rsqrt(var+eps), c = be - mean*a
__device__ inline void bn_affine(float sum, float sumsq, float g, float be,
                                 float inv_n, float& a, float& c) {
  float mean = sum * inv_n;
  float var = sumsq * inv_n - mean * mean;
  a = g * rsqrtf(var + EPS_);
  c = be - mean * a;
}

// ---------------- kernels ----------------

// Fused prep: tobf [0,16384) | count [16384,17408) | wt1 [17408,17920)
//             wt2 [17920,18944) | pnorm [18944,18946)
#define PREP_BLOCKS 18946
__global__ __launch_bounds__(256) void k_prep(const float* __restrict__ x,
                                              const int* __restrict__ dstv,
                                              const float* __restrict__ W1,
                                              const float* __restrict__ W2,
                                              const float* __restrict__ p1,
                                              const float* __restrict__ p2,
                                              unsigned short* __restrict__ xbf,
                                              int* __restrict__ cnt,
                                              unsigned short* __restrict__ Wt1,
                                              unsigned short* __restrict__ Wt2,
                                              float* __restrict__ pn) {
  __shared__ float sh[32][33];
  __shared__ float red[256];
  int bid = blockIdx.x, t = threadIdx.x;
  if (bid < 16384) {                      // fp32 -> bf16 convert of x
    size_t i = ((size_t)bid * 256 + t) * 4;
    float4 v = *(const float4*)&x[i];
    ushort4 o = {f2bf(v.x), f2bf(v.y), f2bf(v.z), f2bf(v.w)};
    *(ushort4*)&xbf[i] = o;
  } else if (bid < 17408) {               // edge dst count
    int e = (bid - 16384) * 256 + t;
    atomicAdd(&cnt[dstv[e]], 1);
  } else if (bid < 18944) {               // weight transpose -> bf16
    const float* W; unsigned short* Wt; int K, N, r;
    if (bid < 17920) { W = W1; Wt = Wt1; K = FIN_; N = H_; r = bid - 17408; }
    else             { W = W2; Wt = Wt2; K = H_;   N = H_; r = bid - 17920; }
    int bx = r & 31, by = r >> 5;
    int k0 = by * 32, n0 = bx * 32;
    int tx = t & 31, ty = t >> 5;
    for (int i = ty; i < 32; i += 8)
      sh[i][tx] = W[(size_t)(k0 + i) * N + n0 + tx];
    __syncthreads();
    for (int i = ty; i < 32; i += 8)
      Wt[(size_t)(n0 + i) * K + k0 + tx] = f2bf(sh[tx][i]);
  } else {                                // pnorm
    const float* p = (bid == 18944) ? p1 : p2;
    float s = 0.f;
    for (int i = t; i < H_; i += 256) s += p[i] * p[i];
    red[t] = s; __syncthreads();
    for (int st = 128; st > 0; st >>= 1) { if (t < st) red[t] += red[t + st]; __syncthreads(); }
    if (t == 0) pn[bid - 18944] = sqrtf(red[0]);
  }
}

// Per-graph exclusive scan: ptr[g*nper + i] = g*ECAP_ + prefix(cnt within graph g).
__global__ __launch_bounds__(256) void k_scan_g(const int* __restrict__ cnt,
                                                int* __restrict__ ptr, int nper) {
  __shared__ int tot[256];
  int g = blockIdx.x, t = threadIdx.x;
  int chunk = nper / 256;
  int base = g * nper + t * chunk;
  int loc[4];
  int s = 0;
  for (int i = 0; i < chunk; ++i) { loc[i] = s; s += cnt[base + i]; }
  tot[t] = s;
  __syncthreads();
  for (int off = 1; off < 256; off <<= 1) {
    int v = (t >= off) ? tot[t - off] : 0;
    __syncthreads();
    tot[t] += v;
    __syncthreads();
  }
  int pre = (t == 0) ? 0 : tot[t - 1];
  int gbase = g * ECAP_;
  for (int i = 0; i < chunk; ++i) ptr[base + i] = gbase + pre + loc[i];
}

__global__ void k_fill(const int* __restrict__ src, const int* __restrict__ dst,
                       const int* __restrict__ ptr, int* __restrict__ fill,
                       int* __restrict__ csr) {
  int e = blockIdx.x * 256 + threadIdx.x;
  int d = dst[e];
  int pos = ptr[d] + atomicAdd(&fill[d], 1);
  csr[pos] = src[e];
}

// Build stage-2 CSR from stage-1 CSR: one wave per kept node i; filter
// csr1[perm1[i]] through newid, ballot-compact into csr2[i*CAP2_..].
__global__ __launch_bounds__(256) void k_build2(const int* __restrict__ perm1,
                                                const int* __restrict__ newid,
                                                const int* __restrict__ ptr1,
                                                const int* __restrict__ cnt1,
                                                const int* __restrict__ csr1,
                                                int* __restrict__ csr2,
                                                int* __restrict__ ptr2,
                                                int* __restrict__ cnt2) {
  int i = blockIdx.x * 4 + (threadIdx.x >> 6);
  int lane = threadIdx.x & 63;
  int old = perm1[i];
  int e0 = ptr1[old], n = cnt1[old];
  int base = i * CAP2_;
  int total = 0;
  for (int b = 0; b < n; b += 64) {
    int l = b + lane;
    int ns = -1;
    if (l < n) ns = newid[csr1[e0 + l]];
    bool valid = (l < n) && (ns >= 0);
    unsigned long long mask = __ballot(valid);
    int pos = __popcll(mask & ((1ull << lane) - 1ull));
    if (valid && total + pos < CAP2_) csr2[base + total + pos] = ns;
    total += __popcll(mask);
  }
  if (lane == 0) { cnt2[i] = (total < CAP2_) ? total : CAP2_; ptr2[i] = base; }
}

// Aggregation (bf16 in -> bf16 out), XCD-swizzled slabs, 16B/lane gathers.
// blockDim = F/8.
__global__ void k_agg_bf(const unsigned short* __restrict__ X,
                         const int* __restrict__ csr,
                         const int* __restrict__ ptr,
                         const int* __restrict__ cnt,
                         unsigned short* __restrict__ out, int F) {
  int bid = blockIdx.x;
  int slab = gridDim.x >> 3;
  int v = (bid & 7) * slab + (bid >> 3);
  int wi = threadIdx.x * 4;              // word index within row (F/2 words)
  const uint32_t* Xw = (const uint32_t*)X;
  int Fw = F >> 1;
  float degv = 1.0f + (float)cnt[v];
  float dinvv = rsqrtf(degv);
  float inv = 1.0f / degv;
  uint4 xu = *(const uint4*)&Xw[(size_t)v * Fw + wi];
  float acc[8];
  acc[0] = bflo(xu.x) * inv; acc[1] = bfhi(xu.x) * inv;
  acc[2] = bflo(xu.y) * inv; acc[3] = bfhi(xu.y) * inv;
  acc[4] = bflo(xu.z) * inv; acc[5] = bfhi(xu.z) * inv;
  acc[6] = bflo(xu.w) * inv; acc[7] = bfhi(xu.w) * inv;
  int e0 = ptr[v], e1 = e0 + cnt[v];
  for (int e = e0; e < e1; ++e) {
    int s = csr[e];
    float w = dinvv * rsqrtf(1.0f + (float)cnt[s]);
    uint4 xs = *(const uint4*)&Xw[(size_t)s * Fw + wi];
    acc[0] += bflo(xs.x) * w; acc[1] += bfhi(xs.x) * w;
    acc[2] += bflo(xs.y) * w; acc[3] += bfhi(xs.y) * w;
    acc[4] += bflo(xs.z) * w; acc[5] += bfhi(xs.z) * w;
    acc[6] += bflo(xs.w) * w; acc[7] += bfhi(xs.w) * w;
  }
  uint4 o = {pack2(acc[0], acc[1]), pack2(acc[2], acc[3]),
             pack2(acc[4], acc[5]), pack2(acc[6], acc[7])};
  *(uint4*)&((uint32_t*)out)[(size_t)v * Fw + wi] = o;
}

// bf16 MFMA GEMM: 256(m) x 128(n) tile, BK=64 (XOR-swizzled segments),
// 512 threads = 8 waves (4x2). bf16 C via LDS-staged coalesced stores;
// fused per-column sum/sumsq; XCD-banded m-tiles.
__global__ __launch_bounds__(512) void k_gemm_bf(const unsigned short* __restrict__ A,
                                                 const unsigned short* __restrict__ Bt,
                                                 const float* __restrict__ bias,
                                                 unsigned short* __restrict__ C,
                                                 float* __restrict__ bn,
                                                 int M, int N, int K) {
  __shared__ __align__(16) char smem[49152];            // 48 KiB
  unsigned short* sA  = (unsigned short*)smem;          // 256x64 = 32 KiB
  unsigned short* sB  = (unsigned short*)(smem + 256 * 64 * 2);  // 128x64 = 16 KiB
  unsigned short* epi = (unsigned short*)smem;          // 128x136 (epilogue, 34 KiB)

  const int tid = threadIdx.x;
  const int lane = tid & 63;
  const int w = tid >> 6;
  const int wy = w >> 1, wx = w & 1;
  int lin = blockIdx.y * gridDim.x + blockIdx.x;
  int nt = gridDim.x;
  int mchunk = gridDim.y >> 3;
  int xcd = lin & 7;
  int idx = lin >> 3;
  int mtile = xcd * mchunk + idx / nt;
  int ntile = idx % nt;
  const int gm = mtile * 256, gn = ntile * 128;

  const int m_l = lane & 15, kq = lane >> 4;
  const int srow = lane >> 3;           // 0..7: row within 8-row chunk
  const int ssegi = lane & 7;           // 0..7: LDS segment slot

  f32x4 acc[4][4] = {};

  for (int k0 = 0; k0 < K; k0 += 64) {
    __syncthreads();
#pragma unroll
    for (int i = 0; i < 4; ++i) {
      int row = w * 32 + i * 8 + srow;
      int gseg = ssegi ^ (row & 7);
      load_lds16(&A[(size_t)(gm + row) * K + k0 + gseg * 8],
                 (void*)&sA[(size_t)(w * 32 + i * 8) * 64 + (size_t)lane * 8]);
    }
#pragma unroll
    for (int i = 0; i < 2; ++i) {
      int row = w * 16 + i * 8 + srow;
      int gseg = ssegi ^ (row & 7);
      load_lds16(&Bt[(size_t)(gn + row) * K + k0 + gseg * 8],
                 (void*)&sB[(size_t)(w * 16 + i * 8) * 64 + (size_t)lane * 8]);
    }
    __syncthreads();

#pragma unroll
    for (int h = 0; h < 2; ++h) {
      short8 af[4], bfr[4];
      int gseg = h * 4 + kq;
#pragma unroll
      for (int mi = 0; mi < 4; ++mi) {
        int row = wy * 64 + mi * 16 + m_l;
        int s = gseg ^ (row & 7);
        af[mi] = *(const short8*)&sA[(size_t)row * 64 + s * 8];
      }
#pragma unroll
      for (int ni = 0; ni < 4; ++ni) {
        int row = wx * 64 + ni * 16 + m_l;
        int s = gseg ^ (row & 7);
        bfr[ni] = *(const short8*)&sB[(size_t)row * 64 + s * 8];
      }
#pragma unroll
      for (int mi = 0; mi < 4; ++mi)
#pragma unroll
        for (int ni = 0; ni < 4; ++ni)
          acc[mi][ni] = __builtin_amdgcn_mfma_f32_16x16x32_bf16(af[mi], bfr[ni], acc[mi][ni], 0, 0, 0);
    }
  }

  const int r0 = kq * 4;   // C/D: col = lane&15, row = (lane>>4)*4 + reg
  float bvv[4];
#pragma unroll
  for (int ni = 0; ni < 4; ++ni) {
    int col = gn + wx * 64 + ni * 16 + m_l;
    bvv[ni] = bias[col];
    float s = 0.f, s2 = 0.f;
#pragma unroll
    for (int mi = 0; mi < 4; ++mi)
#pragma unroll
      for (int r = 0; r < 4; ++r) {
        float v = acc[mi][ni][r] + bvv[ni];
        s += v; s2 += v * v;
      }
    s += __shfl_xor(s, 16, 64);  s2 += __shfl_xor(s2, 16, 64);
    s += __shfl_xor(s, 32, 64);  s2 += __shfl_xor(s2, 32, 64);
    if (kq == 0) {
      atomicAdd(&bn[col], s);
      atomicAdd(&bn[N + col], s2);
    }
  }

  // two-phase LDS-staged coalesced C write
#pragma unroll
  for (int p = 0; p < 2; ++p) {
    __syncthreads();
    if ((wy >> 1) == p) {
      int lr = (wy & 1) * 64;
#pragma unroll
      for (int ni = 0; ni < 4; ++ni) {
        int lcol = wx * 64 + ni * 16 + m_l;
#pragma unroll
        for (int mi = 0; mi < 4; ++mi)
#pragma unroll
          for (int r = 0; r < 4; ++r)
            epi[(size_t)(lr + mi * 16 + r0 + r) * 136 + lcol] = f2bf(acc[mi][ni][r] + bvv[ni]);
      }
    }
    __syncthreads();
#pragma unroll
    for (int i = 0; i < 4; ++i) {
      int cch = tid + i * 512;
      int row = cch >> 4, seg = cch & 15;
      uint4 v = *(const uint4*)&epi[(size_t)row * 136 + seg * 8];
      *(uint4*)&C[(size_t)(gm + p * 128 + row) * N + gn + seg * 8] = v;
    }
  }
}

// score[v] = tanh(dot(relu(x*a+c), p)/||p||); bn affine computed from raw sums
__global__ __launch_bounds__(256) void k_score(const unsigned short* __restrict__ X,
                                               const float* __restrict__ bnsum,
                                               const float* __restrict__ gam,
                                               const float* __restrict__ bet,
                                               float inv_n,
                                               const float* __restrict__ p,
                                               const float* __restrict__ pnorm,
                                               float* __restrict__ score) {
  __shared__ float wred[4];
  int v = blockIdx.x;
  int t = threadIdx.x;
  int c = t * 4;
  float4 sm = *(const float4*)&bnsum[c];
  float4 sq = *(const float4*)&bnsum[H_ + c];
  float4 gg = *(const float4*)&gam[c];
  float4 bb = *(const float4*)&bet[c];
  float a0, c0, a1, c1, a2, c2, a3, c3;
  bn_affine(sm.x, sq.x, gg.x, bb.x, inv_n, a0, c0);
  bn_affine(sm.y, sq.y, gg.y, bb.y, inv_n, a1, c1);
  bn_affine(sm.z, sq.z, gg.z, bb.z, inv_n, a2, c2);
  bn_affine(sm.w, sq.w, gg.w, bb.w, inv_n, a3, c3);
  ushort4 xu = *(const ushort4*)&X[(size_t)v * H_ + c];
  float hx = fmaxf(bf2f(xu.x) * a0 + c0, 0.f);
  float hy = fmaxf(bf2f(xu.y) * a1 + c1, 0.f);
  float hz = fmaxf(bf2f(xu.z) * a2 + c2, 0.f);
  float hw = fmaxf(bf2f(xu.w) * a3 + c3, 0.f);
  float4 p4 = *(const float4*)&p[c];
  float s = hx * p4.x + hy * p4.y + hz * p4.z + hw * p4.w;
#pragma unroll
  for (int off = 1; off < 64; off <<= 1) s += __shfl_xor(s, off, 64);
  if ((t & 63) == 0) wred[t >> 6] = s;
  __syncthreads();
  if (t == 0) score[v] = tanhf((wred[0] + wred[1] + wred[2] + wred[3]) / pnorm[0]);
}

// per-graph exact descending bitonic sort (tie: smaller index first), 256 threads
__global__ __launch_bounds__(256) void k_topk(const float* __restrict__ score,
                                              int nper, int k,
                                              int* __restrict__ perm,
                                              float* __restrict__ val,
                                              int* __restrict__ newid) {
  __shared__ float sk[1024];
  __shared__ int si[1024];
  int g = blockIdx.x, t = threadIdx.x;
  for (int i = t; i < nper; i += 256) { sk[i] = score[g * nper + i]; si[i] = i; }
  __syncthreads();
  int pairs = nper >> 1;
  for (int k2 = 2; k2 <= nper; k2 <<= 1) {
    for (int j = k2 >> 1; j > 0; j >>= 1) {
      for (int p = t; p < pairs; p += 256) {
        int i = ((p & ~(j - 1)) << 1) | (p & (j - 1));
        int ix = i | j;
        float a = sk[i], b = sk[ix];
        int ia = si[i], ib = si[ix];
        bool aFirst = (a > b) || (a == b && ia < ib);
        bool dirDesc = ((i & k2) == 0);
        if (dirDesc ? (!aFirst) : aFirst) {
          sk[i] = b; sk[ix] = a; si[i] = ib; si[ix] = ia;
        }
      }
      __syncthreads();
    }
  }
  for (int i = t; i < k; i += 256) {
    perm[g * k + i] = g * nper + si[i];
    val[g * k + i] = sk[i];
    if (newid) newid[g * nper + si[i]] = g * k + i;
  }
}

// hpool[i] = relu(conv[perm[i]]*a+c) * val[i]   (bf16 -> bf16, BN fused from raw sums)
__global__ __launch_bounds__(256) void k_pool_bn(const unsigned short* __restrict__ Hm,
                                                 const float* __restrict__ bnsum,
                                                 const float* __restrict__ gam,
                                                 const float* __restrict__ bet,
                                                 float inv_n,
                                                 const int* __restrict__ perm,
                                                 const float* __restrict__ val,
                                                 unsigned short* __restrict__ out) {
  int i = blockIdx.x;
  int c = threadIdx.x * 4;
  int old = perm[i];
  float vv = val[i];
  float4 sm = *(const float4*)&bnsum[c];
  float4 sq = *(const float4*)&bnsum[H_ + c];
  float4 gg = *(const float4*)&gam[c];
  float4 bb = *(const float4*)&bet[c];
  float a0, c0, a1, c1, a2, c2, a3, c3;
  bn_affine(sm.x, sq.x, gg.x, bb.x, inv_n, a0, c0);
  bn_affine(sm.y, sq.y, gg.y, bb.y, inv_n, a1, c1);
  bn_affine(sm.z, sq.z, gg.z, bb.z, inv_n, a2, c2);
  bn_affine(sm.w, sq.w, gg.w, bb.w, inv_n, a3, c3);
  ushort4 xu = *(const ushort4*)&Hm[(size_t)old * H_ + c];
  ushort4 o = {f2bf(fmaxf(bf2f(xu.x) * a0 + c0, 0.f) * vv),
               f2bf(fmaxf(bf2f(xu.y) * a1 + c1, 0.f) * vv),
               f2bf(fmaxf(bf2f(xu.z) * a2 + c2, 0.f) * vv),
               f2bf(fmaxf(bf2f(xu.w) * a3 + c3, 0.f) * vv)};
  *(ushort4*)&out[(size_t)i * H_ + c] = o;
}

// partial column-mean (bf16 in), z-split; out pre-zeroed fp32
__global__ __launch_bounds__(256) void k_mean(const unsigned short* __restrict__ X,
                                              float* __restrict__ out,
                                              int k, int rows_per_blk) {
  int g = blockIdx.x;
  int col = blockIdx.y * 256 + threadIdx.x;
  int j0 = blockIdx.z * rows_per_blk;
  float s = 0.f;
  for (int j = j0; j < j0 + rows_per_blk; ++j)
    s += bf2f(X[(size_t)(g * k + j) * H_ + col]);
  atomicAdd(&out[g * H_ + col], s / (float)k);
}

// partial scaled column-mean with fused BN+ReLU, z-split; out pre-zeroed
__global__ __launch_bounds__(256) void k_mean_scaled_bn(const unsigned short* __restrict__ X,
                                                        const float* __restrict__ bnsum,
                                                        const float* __restrict__ gam,
                                                        const float* __restrict__ bet,
                                                        float inv_n,
                                                        const int* __restrict__ perm,
                                                        const float* __restrict__ val,
                                                        float* __restrict__ out,
                                                        int k, int rows_per_blk) {
  int g = blockIdx.x;
  int col = blockIdx.y * 256 + threadIdx.x;
  int j0 = blockIdx.z * rows_per_blk;
  float a, cc;
  bn_affine(bnsum[col], bnsum[H_ + col], gam[col], bet[col], inv_n, a, cc);
  float s = 0.f;
  for (int j = j0; j < j0 + rows_per_blk; ++j) {
    int r = perm[g * k + j];
    float h = fmaxf(bf2f(X[(size_t)r * H_ + col]) * a + cc, 0.f);
    s += val[g * k + j] * h;
  }
  atomicAdd(&out[g * H_ + col], s / (float)k);
}

// head part 1: zws[g,t] += sum_{k in z-chunk} (x1+x2)[g,k] * Wf[k,t]
__global__ __launch_bounds__(512) void k_head1(const float* __restrict__ x1,
                                               const float* __restrict__ x2,
                                               const float* __restrict__ Wf,
                                               float* __restrict__ zws) {
  __shared__ float tv[128];
  int g = blockIdx.x, z = blockIdx.y, t = threadIdx.x;
  int k0 = z * 128;
  if (t < 128) tv[t] = x1[g * H_ + k0 + t] + x2[g * H_ + k0 + t];
  __syncthreads();
  float acc = 0.f;
#pragma unroll 8
  for (int k = 0; k < 128; ++k) acc += tv[k] * Wf[(size_t)(k0 + k) * 512 + t];
  atomicAdd(&zws[g * 512 + t], acc);
}

// head part 2: z = relu(zws+bf); out = z@Wf1 + bf1
__global__ __launch_bounds__(512) void k_head2(const float* __restrict__ zws,
                                               const float* __restrict__ bf,
                                               const float* __restrict__ Wf1,
                                               const float* __restrict__ bf1,
                                               float* __restrict__ out) {
  __shared__ float red[512];
  int g = blockIdx.x, t = threadIdx.x;
  float zv = fmaxf(zws[g * 512 + t] + bf[t], 0.f);
  for (int o = 0; o < OUT_; ++o) {
    red[t] = zv * Wf1[t * OUT_ + o];
    __syncthreads();
    for (int s = 256; s > 0; s >>= 1) { if (t < s) red[t] += red[t + s]; __syncthreads(); }
    if (t == 0) out[g * OUT_ + o] = red[0] + bf1[o];
    __syncthreads();
  }
}

// ---------------- launch ----------------
extern "C" void kernel_launch(void* const* d_in, const int* in_sizes, int n_in,
                              void* d_out, int out_size, void* d_ws, size_t ws_size,
                              hipStream_t stream) {
  (void)in_sizes; (void)n_in; (void)out_size; (void)ws_size;
  const float* x   = (const float*)d_in[0];
  const int*   ei  = (const int*)d_in[1];
  const float* W1  = (const float*)d_in[3];
  const float* b1  = (const float*)d_in[4];
  const float* g1  = (const float*)d_in[5];
  const float* be1 = (const float*)d_in[6];
  const float* p1  = (const float*)d_in[7];
  const float* W2  = (const float*)d_in[8];
  const float* b2  = (const float*)d_in[9];
  const float* g2  = (const float*)d_in[10];
  const float* be2 = (const float*)d_in[11];
  const float* p2  = (const float*)d_in[12];
  const float* Wf  = (const float*)d_in[13];
  const float* bf  = (const float*)d_in[14];
  const float* Wf1 = (const float*)d_in[15];
  const float* bf1 = (const float*)d_in[16];
  const int* srcv = ei;
  const int* dstv = ei + E_;

  char* ws = (char*)d_ws;
  unsigned short* conv1 = (unsigned short*)(ws + OFF_CONV1);
  unsigned short* xagg  = (unsigned short*)(ws + OFF_XAGG);
  unsigned short* hagg2 = (unsigned short*)(ws + OFF_XAGG);  // aliases xagg (dead by then)
  unsigned short* hpool = (unsigned short*)(ws + OFF_HPOOL);
  unsigned short* conv2 = (unsigned short*)(ws + OFF_CONV2);
  unsigned short* xbf   = (unsigned short*)(ws + OFF_XBF);
  int* cnt1    = (int*)(ws + OFF_CNT1);
  int* fill1   = (int*)(ws + OFF_FILL1);
  int* cnt2    = (int*)(ws + OFF_CNT2);
  float* bn1   = (float*)(ws + OFF_BN1);
  float* bn2   = (float*)(ws + OFF_BN2);
  int* ptr1    = (int*)(ws + OFF_PTR1);
  int* ptr2    = (int*)(ws + OFF_PTR2);
  int* csr1    = (int*)(ws + OFF_CSR1);
  int* csr2    = (int*)(ws + OFF_CSR2);
  float* sc1   = (float*)(ws + OFF_SC1);
  float* sc2   = (float*)(ws + OFF_SC2);
  int* perm1   = (int*)(ws + OFF_PERM1);
  float* val1  = (float*)(ws + OFF_VAL1);
  int* perm2   = (int*)(ws + OFF_PERM2);
  float* val2  = (float*)(ws + OFF_VAL2);
  int* newid1  = (int*)(ws + OFF_NEWID);
  float* pnorm = (float*)(ws + OFF_PNORM);
  float* x1    = (float*)(ws + OFF_X1);
  float* x2    = (float*)(ws + OFF_X2);
  float* zws   = (float*)(ws + OFF_ZWS);
  unsigned short* Wt1 = (unsigned short*)(ws + OFF_WT1);
  unsigned short* Wt2 = (unsigned short*)(ws + OFF_WT2);

  hipMemsetAsync(ws + ZERO_BASE, 0, ZERO_BYTES, stream);
  hipMemsetAsync(ws + OFF_NEWID, 0xFF, (size_t)NN1_ * 4, stream);  // new_id = -1

  // fused prep: x->bf16, dst count, W1^T, W2^T, pnorms
  k_prep<<<PREP_BLOCKS, 256, 0, stream>>>(x, dstv, W1, W2, p1, p2,
                                          xbf, cnt1, Wt1, Wt2, pnorm);

  // ---- stage 1 ----
  k_scan_g<<<B_, 256, 0, stream>>>(cnt1, ptr1, N_);
  k_fill<<<E_ / 256, 256, 0, stream>>>(srcv, dstv, ptr1, fill1, csr1);
  k_agg_bf<<<NN1_, FIN_ / 8, 0, stream>>>(xbf, csr1, ptr1, cnt1, xagg, FIN_);
  k_gemm_bf<<<dim3(H_ / 128, NN1_ / 256), 512, 0, stream>>>(xagg, Wt1, b1, conv1, bn1, NN1_, H_, FIN_);
  k_score<<<NN1_, 256, 0, stream>>>(conv1, bn1, g1, be1, 1.0f / (float)NN1_, p1, pnorm + 0, sc1);
  k_topk<<<B_, 256, 0, stream>>>(sc1, N_, K1_, perm1, val1, newid1);
  k_pool_bn<<<NN2_, 256, 0, stream>>>(conv1, bn1, g1, be1, 1.0f / (float)NN1_, perm1, val1, hpool);
  k_mean<<<dim3(B_, H_ / 256, 8), 256, 0, stream>>>(hpool, x1, K1_, K1_ / 8);

  // ---- stage 2 ----
  k_build2<<<NN2_ / 4, 256, 0, stream>>>(perm1, newid1, ptr1, cnt1, csr1, csr2, ptr2, cnt2);
  k_agg_bf<<<NN2_, H_ / 8, 0, stream>>>(hpool, csr2, ptr2, cnt2, hagg2, H_);
  k_gemm_bf<<<dim3(H_ / 128, NN2_ / 256), 512, 0, stream>>>(hagg2, Wt2, b2, conv2, bn2, NN2_, H_, H_);
  k_score<<<NN2_, 256, 0, stream>>>(conv2, bn2, g2, be2, 1.0f / (float)NN2_, p2, pnorm + 1, sc2);
  k_topk<<<B_, 256, 0, stream>>>(sc2, K1_, K2_, perm2, val2, nullptr);
  k_mean_scaled_bn<<<dim3(B_, H_ / 256, 4), 256, 0, stream>>>(conv2, bn2, g2, be2, 1.0f / (float)NN2_,
                                                              perm2, val2, x2, K2_, K2_ / 4);

  // ---- head ----
  k_head1<<<dim3(B_, 8), 512, 0, stream>>>(x1, x2, Wf, zws);
  k_head2<<<B_, 512, 0, stream>>>(zws, bf, Wf1, bf1, (float*)d_out);
}